// Round 1
// baseline (1401.980 us; speedup 1.0000x reference)
//
#include <hip/hip_runtime.h>
#include <hip/hip_bf16.h>

#define H_DIM 2048
#define I_DIM 4096
#define NE 8
#define NT 1024

#define BM 128
#define BN 64
#define BK 32
#define LDST 40  // LDS row stride in shorts (32 + 8 pad) -> 80B, ~2-way conflicts max

typedef __bf16 bf16x8 __attribute__((ext_vector_type(8)));
typedef float f32x4 __attribute__((ext_vector_type(4)));
typedef unsigned short u16x8 __attribute__((ext_vector_type(8)));

__device__ __forceinline__ unsigned short f2bf(float f) {
  return __builtin_bit_cast(unsigned short, (__bf16)f);
}

// ---------------- router: 1 wave per token ----------------
__global__ __launch_bounds__(256) void router_kernel(
    const float* __restrict__ x, const float* __restrict__ rw,
    float* __restrict__ rs_out, int* __restrict__ expert_of,
    float* __restrict__ score_of, int* __restrict__ counts)
{
  const int lane = threadIdx.x & 63;
  const int wv = threadIdx.x >> 6;
  const int t = blockIdx.x * 4 + wv;
  float acc[NE];
#pragma unroll
  for (int e = 0; e < NE; ++e) acc[e] = 0.f;
  const float* xr = x + (size_t)t * H_DIM;
  for (int h0 = 0; h0 < H_DIM; h0 += 64) {
    const float xv = xr[h0 + lane];
    const float* rwp = rw + (size_t)(h0 + lane) * NE;
    const f32x4 r0 = *(const f32x4*)rwp;
    const f32x4 r1 = *(const f32x4*)(rwp + 4);
#pragma unroll
    for (int e = 0; e < 4; ++e) { acc[e] += xv * r0[e]; acc[e + 4] += xv * r1[e]; }
  }
#pragma unroll
  for (int e = 0; e < NE; ++e) {
    acc[e] += __shfl_xor(acc[e], 32, 64);
    acc[e] += __shfl_xor(acc[e], 16, 64);
    acc[e] += __shfl_xor(acc[e], 8, 64);
    acc[e] += __shfl_xor(acc[e], 4, 64);
    acc[e] += __shfl_xor(acc[e], 2, 64);
    acc[e] += __shfl_xor(acc[e], 1, 64);
  }
  int best = 0; float bv = acc[0];
#pragma unroll
  for (int e = 1; e < NE; ++e) if (acc[e] > bv) { bv = acc[e]; best = e; }
  const float score = 1.f / (1.f + __expf(-bv));
  if (lane < NE) rs_out[(size_t)lane * NT + t] = (lane == best) ? score : 0.f;
  if (lane == 0) {
    expert_of[t] = best;
    score_of[t] = score;
    atomicAdd(&counts[best], 1);
  }
}

// ---------------- offsets (exclusive prefix over 8 counts) ----------------
__global__ void offsets_kernel(const int* __restrict__ counts,
                               int* __restrict__ offsets, int* __restrict__ cursor)
{
  if (threadIdx.x == 0) {
    int run = 0;
#pragma unroll
    for (int e = 0; e < NE; ++e) { offsets[e] = run; run += counts[e]; cursor[e] = 0; }
  }
}

// ---------------- scatter tokens into per-expert groups ----------------
__global__ void scatter_kernel(const int* __restrict__ expert_of,
                               const int* __restrict__ offsets,
                               int* __restrict__ cursor, int* __restrict__ perm)
{
  const int t = blockIdx.x * 256 + threadIdx.x;
  const int e = expert_of[t];
  const int p = atomicAdd(&cursor[e], 1);
  perm[offsets[e] + p] = t;
}

// ---------------- gather: bf16 x (shared) + score-scaled grouped bf16 x (routed) ----------------
__global__ __launch_bounds__(256) void gather_kernel(
    const float* __restrict__ x, const int* __restrict__ perm,
    const float* __restrict__ score_of, unsigned short* __restrict__ xb,
    unsigned short* __restrict__ xs)
{
  const int b = blockIdx.x;
  const int c = threadIdx.x * 8;
  const int src = perm[b];
  const float s = score_of[src];
  const float* xrow = x + (size_t)b * H_DIM + c;
  const float* srow = x + (size_t)src * H_DIM + c;
  u16x8 vb, vs;
#pragma unroll
  for (int j = 0; j < 8; ++j) {
    vb[j] = f2bf(xrow[j]);
    vs[j] = f2bf(srow[j] * s);
  }
  *(u16x8*)&xb[(size_t)b * H_DIM + c] = vb;
  *(u16x8*)&xs[(size_t)b * H_DIM + c] = vs;
}

// ---------------- GEMM1: act = silu(X@Wg) * (X@Wu), fused, bf16 out ----------------
// A operand = W^T fragments loaded DIRECTLY from fp32 global (no transpose staging):
//   lane l loads W[k0+(l>>4)*8+j][n0+w*16+(l&15)]  (coalesced 64B across 16 lanes per j)
// B operand = X^T fragments from LDS (k-contiguous bf16, ds_read_b128).
// z-block 0..7 = routed experts (grouped, scaled X), z=8 = shared expert.
__global__ __launch_bounds__(256) void gemm1_kernel(
    const unsigned short* __restrict__ xs, const unsigned short* __restrict__ xb,
    const float* __restrict__ gup, const float* __restrict__ sgw,
    const float* __restrict__ suw, unsigned short* __restrict__ act_r,
    unsigned short* __restrict__ act_s, const int* __restrict__ counts,
    const int* __restrict__ offsets)
{
  const int e = blockIdx.z;
  int cnt, roff; size_t ldw;
  const unsigned short* X; const float* Wg; const float* Wu; unsigned short* OUT;
  if (e < NE) {
    cnt = counts[e]; roff = offsets[e]; ldw = 2 * I_DIM;
    X = xs; Wg = gup + (size_t)e * H_DIM * 2 * I_DIM; Wu = Wg + I_DIM; OUT = act_r;
  } else {
    cnt = NT; roff = 0; ldw = I_DIM;
    X = xb; Wg = sgw; Wu = suw; OUT = act_s;
  }
  const int m0 = blockIdx.x * BM;
  if (m0 >= cnt) return;
  const int n0 = blockIdx.y * BN;

  __shared__ unsigned short lds[BM * LDST];

  const int tid = threadIdx.x, lane = tid & 63, w = tid >> 6;
  const int na = n0 + w * 16 + (lane & 15);
  const float* ag = Wg + (size_t)((lane >> 4) * 8) * ldw + na;
  const float* au = Wu + (size_t)((lane >> 4) * 8) * ldw + na;

  f32x4 accg[8] = {};
  f32x4 accu[8] = {};

  const int ldsro = (lane & 15) * LDST + (lane >> 4) * 8;
  const int sr = tid >> 2, sc = (tid & 3) * 8;
  const unsigned short* Xr = X + (size_t)roff * H_DIM;

  for (int k0 = 0; k0 < H_DIM; k0 += BK) {
    __syncthreads();
#pragma unroll
    for (int it = 0; it < 2; ++it) {
      const int r = sr + it * 64;
      const int m = m0 + r;
      u16x8 v = {0, 0, 0, 0, 0, 0, 0, 0};
      if (m < cnt) v = *(const u16x8*)(Xr + (size_t)m * H_DIM + k0 + sc);
      *(u16x8*)&lds[r * LDST + sc] = v;
    }
    __syncthreads();

    bf16x8 afg, afu;
#pragma unroll
    for (int j = 0; j < 8; ++j) afg[j] = (__bf16)ag[(size_t)j * ldw];
#pragma unroll
    for (int j = 0; j < 8; ++j) afu[j] = (__bf16)au[(size_t)j * ldw];
    ag += (size_t)BK * ldw; au += (size_t)BK * ldw;

#pragma unroll
    for (int mb = 0; mb < 8; ++mb) {
      const u16x8 braw = *(const u16x8*)&lds[mb * 16 * LDST + ldsro];
      const bf16x8 bfr = __builtin_bit_cast(bf16x8, braw);
      accg[mb] = __builtin_amdgcn_mfma_f32_16x16x32_bf16(afg, bfr, accg[mb], 0, 0, 0);
      accu[mb] = __builtin_amdgcn_mfma_f32_16x16x32_bf16(afu, bfr, accu[mb], 0, 0, 0);
    }
  }

  // D layout: row(n) = (lane>>4)*4 + reg, col(m) = lane&15   [verified m89/m91]
  const int nw = n0 + w * 16 + ((lane >> 4) * 4);
#pragma unroll
  for (int mb = 0; mb < 8; ++mb) {
    const int m = m0 + mb * 16 + (lane & 15);
    if (m < cnt) {
      unsigned short o[4];
#pragma unroll
      for (int r = 0; r < 4; ++r) {
        const float g = accg[mb][r];
        const float u = accu[mb][r];
        const float sg = g / (1.f + __expf(-g));
        o[r] = f2bf(sg * u);
      }
      uint2 pk;
      pk.x = (unsigned)o[0] | ((unsigned)o[1] << 16);
      pk.y = (unsigned)o[2] | ((unsigned)o[3] << 16);
      *(uint2*)&OUT[(size_t)(roff + m) * I_DIM + nw] = pk;
    }
  }
}

// ---------------- GEMM2: out[t] (+)= act @ Wd ----------------
__global__ __launch_bounds__(256) void gemm2_kernel(
    const unsigned short* __restrict__ ACT, const float* __restrict__ wd_base,
    float* __restrict__ OUT, const int* __restrict__ counts,
    const int* __restrict__ offsets, const int* __restrict__ perm,
    const int accumulate)
{
  const int e = blockIdx.z;
  const int cnt = counts ? counts[e] : NT;
  const int roff = offsets ? offsets[e] : 0;
  const int m0 = blockIdx.x * BM;
  if (m0 >= cnt) return;
  const int n0 = blockIdx.y * BN;
  const float* Wd = wd_base + (size_t)e * I_DIM * H_DIM;

  __shared__ unsigned short lds[BM * LDST];

  const int tid = threadIdx.x, lane = tid & 63, w = tid >> 6;
  const int na = n0 + w * 16 + (lane & 15);
  const float* ad = Wd + (size_t)((lane >> 4) * 8) * H_DIM + na;

  f32x4 acc[8] = {};

  const int ldsro = (lane & 15) * LDST + (lane >> 4) * 8;
  const int sr = tid >> 2, sc = (tid & 3) * 8;
  const unsigned short* Xr = ACT + (size_t)roff * I_DIM;

  for (int k0 = 0; k0 < I_DIM; k0 += BK) {
    __syncthreads();
#pragma unroll
    for (int it = 0; it < 2; ++it) {
      const int r = sr + it * 64;
      const int m = m0 + r;
      u16x8 v = {0, 0, 0, 0, 0, 0, 0, 0};
      if (m < cnt) v = *(const u16x8*)(Xr + (size_t)m * I_DIM + k0 + sc);
      *(u16x8*)&lds[r * LDST + sc] = v;
    }
    __syncthreads();

    bf16x8 af;
#pragma unroll
    for (int j = 0; j < 8; ++j) af[j] = (__bf16)ad[(size_t)j * H_DIM];
    ad += (size_t)BK * H_DIM;

#pragma unroll
    for (int mb = 0; mb < 8; ++mb) {
      const u16x8 braw = *(const u16x8*)&lds[mb * 16 * LDST + ldsro];
      const bf16x8 bfr = __builtin_bit_cast(bf16x8, braw);
      acc[mb] = __builtin_amdgcn_mfma_f32_16x16x32_bf16(af, bfr, acc[mb], 0, 0, 0);
    }
  }

  const int nw = n0 + w * 16 + ((lane >> 4) * 4);
#pragma unroll
  for (int mb = 0; mb < 8; ++mb) {
    const int m = m0 + mb * 16 + (lane & 15);
    if (m < cnt) {
      const int t = perm ? perm[roff + m] : m;
      float* orow = OUT + (size_t)t * H_DIM + nw;
      f32x4 v = acc[mb];
      if (accumulate) {
        const f32x4 old = *(const f32x4*)orow;
        v += old;
      }
      *(f32x4*)orow = v;
    }
  }
}

extern "C" void kernel_launch(void* const* d_in, const int* in_sizes, int n_in,
                              void* d_out, int out_size, void* d_ws, size_t ws_size,
                              hipStream_t stream)
{
  const float* x   = (const float*)d_in[0];
  const float* rw  = (const float*)d_in[1];
  const float* gup = (const float*)d_in[2];
  const float* dwn = (const float*)d_in[3];
  const float* sgw = (const float*)d_in[4];
  const float* suw = (const float*)d_in[5];
  const float* sdw = (const float*)d_in[6];
  float* out = (float*)d_out;
  float* rs_out = out + (size_t)NT * H_DIM;   // router_scores [E][T] after out [T][H]

  char* ws = (char*)d_ws;
  int* counts   = (int*)ws;               // 32 B
  int* cursor   = (int*)(ws + 32);        // 32 B
  int* offsets  = (int*)(ws + 64);        // 32 B
  int* expert_of = (int*)(ws + 128);      // 4 KB
  float* score_of = (float*)(ws + 128 + 4096);
  int* perm     = (int*)(ws + 128 + 8192);
  unsigned short* xb    = (unsigned short*)(ws + 16384);       // [T][H] bf16 (4 MB)
  unsigned short* xs    = xb + (size_t)NT * H_DIM;             // grouped scaled (4 MB)
  unsigned short* act_s = xs + (size_t)NT * H_DIM;             // [T][I] bf16 (8 MB)
  unsigned short* act_r = act_s + (size_t)NT * I_DIM;          // [T][I] bf16 (8 MB)

  hipMemsetAsync(counts, 0, 64, stream);
  router_kernel<<<dim3(NT / 4), dim3(256), 0, stream>>>(x, rw, rs_out, expert_of, score_of, counts);
  offsets_kernel<<<dim3(1), dim3(64), 0, stream>>>(counts, offsets, cursor);
  scatter_kernel<<<dim3(NT / 256), dim3(256), 0, stream>>>(expert_of, offsets, cursor, perm);
  gather_kernel<<<dim3(NT), dim3(256), 0, stream>>>(x, perm, score_of, xb, xs);
  gemm1_kernel<<<dim3(NT / BM, I_DIM / BN, NE + 1), dim3(256), 0, stream>>>(
      xs, xb, gup, sgw, suw, act_r, act_s, counts, offsets);
  gemm2_kernel<<<dim3(NT / BM, H_DIM / BN, 1), dim3(256), 0, stream>>>(
      act_s, sdw, out, nullptr, nullptr, nullptr, 0);
  gemm2_kernel<<<dim3(NT / BM, H_DIM / BN, NE), dim3(256), 0, stream>>>(
      act_r, dwn, out, counts, offsets, perm, 1);
}